// Round 3
// baseline (283.333 us; speedup 1.0000x reference)
//
#include <hip/hip_runtime.h>

typedef unsigned short u16;
typedef unsigned int u32;
typedef unsigned long long u64;
typedef __attribute__((ext_vector_type(2))) float f32x2;
typedef __attribute__((ext_vector_type(4))) float f32x4;
typedef __attribute__((ext_vector_type(8))) u16 u16x8;
typedef __attribute__((ext_vector_type(8))) __bf16 bf16x8;

#define IN_F 512
#define OUT_F 512
#define KTOT 4608   // 512 silu + 512*8 spline bases
#define BM 128
#define BN 256
#define BK 64
#define NKT 72
#define NSIL 8      // first 8 k-tiles are the silu region
#define LDSS 72     // padded LDS row stride in u16 (144B)

__device__ __forceinline__ u16 f2bf(float f) {
  u32 u = __float_as_uint(f);
  return (u16)((u + 0x7FFFu + ((u >> 16) & 1u)) >> 16);  // RNE
}
__device__ __forceinline__ float siluf(float v) { return v / (1.0f + __expf(-v)); }

// Uniform-knot cubic B-spline: 8 bf16 bases of x packed into (lo,hi) 128-bit.
__device__ __forceinline__ void spline8(float xv, u64& lo, u64& hi) {
  float u = fmaf(xv, 2.5f, 5.5f);
  float cf = floorf(u);
  float f = u - cf;
  int c = (int)cf;
  bool valid = (u >= 0.0f) && (u < 11.0f);
  c = c < 0 ? 0 : (c > 10 ? 10 : c);
  float f2 = f * f, f3 = f2 * f;
  float v1 = 1.0f - f;
  float w0 = v1 * v1 * v1 * (1.0f / 6.0f);
  float w1 = 0.5f * f3 - f2 + (2.0f / 3.0f);
  float w2 = -0.5f * f3 + 0.5f * f2 + 0.5f * f + (1.0f / 6.0f);
  float w3 = f3 * (1.0f / 6.0f);
  u64 W = (u64)f2bf(w0) | ((u64)f2bf(w1) << 16) | ((u64)f2bf(w2) << 32) |
          ((u64)f2bf(w3) << 48);
  if (!valid) W = 0;
  const int s = c * 16 - 48;
  if (s < 0)       { lo = W >> (-s); hi = 0; }
  else if (s == 0) { lo = W;         hi = 0; }
  else if (s < 64) { lo = W << s;    hi = W >> (64 - s); }
  else             { lo = 0;         hi = W << (s - 64); }
}

// Wc[o][k] bf16: k<512 -> base_weight; else spline_weight*scaler
__global__ __launch_bounds__(256) void kan_prep(const float* __restrict__ bw,
                                                const float* __restrict__ sw,
                                                const float* __restrict__ ss,
                                                u16* __restrict__ Wc) {
  const int t = blockIdx.x * 256 + threadIdx.x;  // o*512 + i
  const int o = t >> 9, i = t & 511;
  const float s = ss[t];
  const float* sp = sw + (size_t)t * 8;
  f32x4 s0 = *(const f32x4*)sp;
  f32x4 s1 = *(const f32x4*)(sp + 4);
  u16x8 p;
#pragma unroll
  for (int e = 0; e < 4; ++e) {
    p[e] = f2bf(s0[e] * s);
    p[4 + e] = f2bf(s1[e] * s);
  }
  *(u16x8*)&Wc[(size_t)o * KTOT + IN_F + i * 8] = p;
  Wc[(size_t)o * KTOT + i] = f2bf(bw[t]);
}

__global__ __launch_bounds__(512, 2) void kan_gemm(const float* __restrict__ x,
                                                   const u16* __restrict__ Wc,
                                                   float* __restrict__ out) {
  __shared__ u16 As[2][BM * LDSS];
  const int tid = threadIdx.x;
  const int b = blockIdx.x;
  // bijective swizzle: n-half from bit2 (XCDs 0-3 -> n0=0, 4-7 -> n0=256, L2-resident half)
  const int n0 = ((b >> 2) & 1) * BN;
  const int m0 = ((b & 3) | ((b >> 3) << 2)) * BM;

  const int lane = tid & 63;
  const int wv = tid >> 6;   // 8 waves: 2 rows x 4 cols of 64x64 tiles
  const int wr = wv >> 2;
  const int wc = wv & 3;
  const int lr = lane & 15;
  const int lk = lane >> 4;

  // B direct-to-register base (MFMA fragment layout)
  const u16* bptr = Wc + (size_t)(n0 + wc * 64 + lr) * KTOT + lk * 8;

  // A staging: thread -> row tid>>2, segment tid&3
  const int arow = tid >> 2;
  const int aseg = tid & 3;
  const float* xrow = x + (size_t)(m0 + arow) * IN_F;

  f32x4 acc[4][4];
  const f32x4 zero = {0.0f, 0.0f, 0.0f, 0.0f};
#pragma unroll
  for (int m = 0; m < 4; ++m)
#pragma unroll
    for (int n = 0; n < 4; ++n) acc[m][n] = zero;

  bf16x8 brA[8], brB[8];   // [n*2+s], ping-pong sets (all indices compile-time)

#define LOADB(REG, KT)                                                       \
  {                                                                          \
    const u16* p_ = bptr + (size_t)(KT) * BK;                                \
    _Pragma("unroll") for (int n_ = 0; n_ < 4; ++n_) {                       \
      REG[n_ * 2]     = *(const bf16x8*)(p_ + (size_t)n_ * 16 * KTOT);       \
      REG[n_ * 2 + 1] = *(const bf16x8*)(p_ + (size_t)n_ * 16 * KTOT + 32);  \
    }                                                                        \
  }

#define STAGEA(BUF, KT)                                                      \
  if ((KT) < NSIL) {                                                         \
    const float* xs_ = xrow + (KT) * BK + aseg * 16;                         \
    _Pragma("unroll") for (int q_ = 0; q_ < 2; ++q_) {                       \
      f32x4 v0_ = *(const f32x4*)(xs_ + q_ * 8);                             \
      f32x4 v1_ = *(const f32x4*)(xs_ + q_ * 8 + 4);                         \
      u16x8 pk_;                                                             \
      _Pragma("unroll") for (int e_ = 0; e_ < 4; ++e_) {                     \
        pk_[e_] = f2bf(siluf(v0_[e_]));                                      \
        pk_[4 + e_] = f2bf(siluf(v1_[e_]));                                  \
      }                                                                      \
      *(u16x8*)&As[BUF][arow * LDSS + aseg * 16 + q_ * 8] = pk_;             \
    }                                                                        \
  } else {                                                                   \
    const int i0_ = (KT) * 8 - 64;                                           \
    f32x2 xv_ = *(const f32x2*)(xrow + i0_ + aseg * 2);                      \
    _Pragma("unroll") for (int e_ = 0; e_ < 2; ++e_) {                       \
      u64 lo_, hi_;                                                          \
      spline8(xv_[e_], lo_, hi_);                                            \
      union { struct { u64 a, b; } q; u16x8 v; } uu_;                        \
      uu_.q.a = lo_; uu_.q.b = hi_;                                          \
      *(u16x8*)&As[BUF][arow * LDSS + (aseg * 2 + e_) * 8] = uu_.v;          \
    }                                                                        \
  }

#define COMPUTE(BUF, BREG)                                                   \
  _Pragma("unroll") for (int s_ = 0; s_ < 2; ++s_) {                         \
    bf16x8 af_[4];                                                           \
    _Pragma("unroll") for (int m_ = 0; m_ < 4; ++m_)                         \
      af_[m_] = *(const bf16x8*)&As[BUF][(wr * 64 + m_ * 16 + lr) * LDSS +   \
                                         s_ * 32 + lk * 8];                  \
    _Pragma("unroll") for (int m_ = 0; m_ < 4; ++m_)                         \
      _Pragma("unroll") for (int n_ = 0; n_ < 4; ++n_)                       \
        acc[m_][n_] = __builtin_amdgcn_mfma_f32_16x16x32_bf16(               \
            af_[m_], BREG[n_ * 2 + s_], acc[m_][n_], 0, 0, 0);               \
  }

  // prologue: tile 0 staged + B regs for tile 0
  LOADB(brA, 0);
  STAGEA(0, 0);
  __syncthreads();

  for (int kt = 0; kt < NKT; kt += 2) {
    // even: compute buf0/brA, stage kt+1 into buf1/brB
    LOADB(brB, kt + 1);          // kt+1 <= 71 always
    COMPUTE(0, brA);
    STAGEA(1, kt + 1);
    __syncthreads();
    // odd: compute buf1/brB, stage kt+2 into buf0/brA
    if (kt + 2 < NKT) {
      LOADB(brA, kt + 2);
      COMPUTE(1, brB);
      STAGEA(0, kt + 2);
    } else {
      COMPUTE(1, brB);
    }
    __syncthreads();
  }

  // epilogue: C/D layout col=lane&15, row=(lane>>4)*4+j
#pragma unroll
  for (int m = 0; m < 4; ++m)
#pragma unroll
    for (int n = 0; n < 4; ++n)
#pragma unroll
      for (int j = 0; j < 4; ++j)
        out[(size_t)(m0 + wr * 64 + m * 16 + lk * 4 + j) * OUT_F + n0 +
            wc * 64 + n * 16 + lr] = acc[m][n][j];

#undef LOADB
#undef STAGEA
#undef COMPUTE
}

extern "C" void kernel_launch(void* const* d_in, const int* in_sizes, int n_in,
                              void* d_out, int out_size, void* d_ws, size_t ws_size,
                              hipStream_t stream) {
  const float* x  = (const float*)d_in[0];
  const float* bw = (const float*)d_in[1];
  const float* sw = (const float*)d_in[2];
  const float* ss = (const float*)d_in[3];
  u16* Wc = (u16*)d_ws;  // 4.72 MB

  kan_prep<<<dim3(OUT_F * IN_F / 256), 256, 0, stream>>>(bw, sw, ss, Wc);
  kan_gemm<<<dim3(256), 512, 0, stream>>>(x, Wc, (float*)d_out);
}

// Round 4
// 211.104 us; speedup vs baseline: 1.3422x; 1.3422x over previous
//
#include <hip/hip_runtime.h>

typedef unsigned short u16;
typedef unsigned int u32;
typedef unsigned long long u64;
typedef __attribute__((ext_vector_type(4))) float f32x4;
typedef __attribute__((ext_vector_type(8))) u16 u16x8;
typedef __attribute__((ext_vector_type(8))) __bf16 bf16x8;

#define IN_F 512
#define OUT_F 512
#define BM 64
#define BN 512
#define BK 64
#define NKT 72      // 72 k-tiles of 64: 8 silu + 64 spline
#define NSIL 8

__device__ __forceinline__ u16 f2bf(float f) {
  u32 u = __float_as_uint(f);
  return (u16)((u + 0x7FFFu + ((u >> 16) & 1u)) >> 16);  // RNE
}
__device__ __forceinline__ float siluf(float v) { return v / (1.0f + __expf(-v)); }

// Uniform-knot cubic B-spline: 8 bf16 bases of x packed into (lo,hi) 128-bit.
__device__ __forceinline__ void spline8(float xv, u64& lo, u64& hi) {
  float u = fmaf(xv, 2.5f, 5.5f);
  float cf = floorf(u);
  float f = u - cf;
  int c = (int)cf;
  bool valid = (u >= 0.0f) && (u < 11.0f);
  c = c < 0 ? 0 : (c > 10 ? 10 : c);
  float f2 = f * f, f3 = f2 * f;
  float v1 = 1.0f - f;
  float w0 = v1 * v1 * v1 * (1.0f / 6.0f);
  float w1 = 0.5f * f3 - f2 + (2.0f / 3.0f);
  float w2 = -0.5f * f3 + 0.5f * f2 + 0.5f * f + (1.0f / 6.0f);
  float w3 = f3 * (1.0f / 6.0f);
  u64 W = (u64)f2bf(w0) | ((u64)f2bf(w1) << 16) | ((u64)f2bf(w2) << 32) |
          ((u64)f2bf(w3) << 48);
  if (!valid) W = 0;
  const int s = c * 16 - 48;
  if (s < 0)       { lo = W >> (-s); hi = 0; }
  else if (s == 0) { lo = W;         hi = 0; }
  else if (s < 64) { lo = W << s;    hi = W >> (64 - s); }
  else             { lo = 0;         hi = W << (s - 64); }
}

// Fragment-ordered weights: for k-octet g (k = g*8+e) and out-col o:
//   u16 index = ((g>>2)*32 + (o>>4))*512 + (g&3)*128 + (o&15)*8 + e
// so a wave's B-frag load (fixed kt,s,n; lane=(lk,lr)) is one contiguous 1KB.
__global__ __launch_bounds__(256) void kan_prep(const float* __restrict__ bw,
                                                const float* __restrict__ sw,
                                                const float* __restrict__ ss,
                                                u16* __restrict__ Wf) {
  const int t = blockIdx.x * 256 + threadIdx.x;  // o*512 + i
  const int o = t >> 9, i = t & 511;
  const float s = ss[t];
  const float* sp = sw + (size_t)t * 8;
  f32x4 s0 = *(const f32x4*)sp;
  f32x4 s1 = *(const f32x4*)(sp + 4);
  u16x8 p;
#pragma unroll
  for (int e = 0; e < 4; ++e) {
    p[e] = f2bf(s0[e] * s);
    p[4 + e] = f2bf(s1[e] * s);
  }
  const int g = 64 + i;
  *(u16x8*)&Wf[((size_t)(g >> 2) * 32 + (o >> 4)) * 512 + (g & 3) * 128 + (o & 15) * 8] = p;
  if (i < 64) {  // base-weight octets g=0..63
    const float* bp = bw + (size_t)o * 512 + i * 8;
    f32x4 b0 = *(const f32x4*)bp;
    f32x4 b1 = *(const f32x4*)(bp + 4);
    u16x8 q;
#pragma unroll
    for (int e = 0; e < 4; ++e) {
      q[e] = f2bf(b0[e]);
      q[4 + e] = f2bf(b1[e]);
    }
    *(u16x8*)&Wf[((size_t)(i >> 2) * 32 + (o >> 4)) * 512 + (i & 3) * 128 + (o & 15) * 8] = q;
  }
}

__global__ __launch_bounds__(512, 2) void kan_gemm(const float* __restrict__ x,
                                                   const u16* __restrict__ Wf,
                                                   float* __restrict__ out) {
  // A in LDS, fragment-ordered: As[buf][oct(8)][row(64)][8 u16] = 8KB per buffer
  __shared__ u16 As[2][8 * 64 * 8];
  const int tid = threadIdx.x;
  const int m0 = blockIdx.x * BM;

  const int lane = tid & 63;
  const int wv = tid >> 6;    // 8 waves, wave wv owns cols wv*64..wv*64+63
  const int lr = lane & 15;
  const int lk = lane >> 4;

  // staging role: wave wv stages octet wv, lane = row
  const float* xrow = x + (size_t)(m0 + lane) * IN_F;

  // B-frag pointer: chunk index = (kt*2+s)*32 + wv*4 + n, each chunk 512 u16
  const u16* bbase = Wf + (size_t)(wv * 4) * 512 + lane * 8;

  f32x4 acc[4][4];
  const f32x4 zero = {0.0f, 0.0f, 0.0f, 0.0f};
#pragma unroll
  for (int m = 0; m < 4; ++m)
#pragma unroll
    for (int n = 0; n < 4; ++n) acc[m][n] = zero;

  bf16x8 brA[8], brB[8];  // [s*4+n] ping-pong

#define LOADB(REG, KT)                                                        \
  {                                                                           \
    const u16* p_ = bbase + (size_t)(KT) * 2 * 32 * 512;                      \
    _Pragma("unroll") for (int s_ = 0; s_ < 2; ++s_)                          \
      _Pragma("unroll") for (int n_ = 0; n_ < 4; ++n_)                        \
        REG[s_ * 4 + n_] = *(const bf16x8*)(p_ + ((size_t)s_ * 32 + n_) * 512);\
  }

#define STAGEA(BUF, KT)                                                       \
  if ((KT) < NSIL) {                                                          \
    const float* xs_ = xrow + (KT) * BK + wv * 8;                             \
    f32x4 v0_ = *(const f32x4*)xs_;                                           \
    f32x4 v1_ = *(const f32x4*)(xs_ + 4);                                     \
    u16x8 pk_;                                                                \
    _Pragma("unroll") for (int e_ = 0; e_ < 4; ++e_) {                        \
      pk_[e_] = f2bf(siluf(v0_[e_]));                                         \
      pk_[4 + e_] = f2bf(siluf(v1_[e_]));                                     \
    }                                                                         \
    *(u16x8*)&As[BUF][(wv * 64 + lane) * 8] = pk_;                            \
  } else {                                                                    \
    float xv_ = xrow[(KT) * 8 - 64 + wv];                                     \
    u64 lo_, hi_;                                                             \
    spline8(xv_, lo_, hi_);                                                   \
    union { struct { u64 a, b; } q; u16x8 v; } uu_;                           \
    uu_.q.a = lo_; uu_.q.b = hi_;                                             \
    *(u16x8*)&As[BUF][(wv * 64 + lane) * 8] = uu_.v;                          \
  }

#define COMPUTE(BUF, BREG)                                                    \
  _Pragma("unroll") for (int s_ = 0; s_ < 2; ++s_) {                          \
    bf16x8 af_[4];                                                            \
    _Pragma("unroll") for (int m_ = 0; m_ < 4; ++m_)                          \
      af_[m_] = *(const bf16x8*)&As[BUF][((s_ * 4 + lk) * 64 + m_ * 16 + lr) * 8];\
    _Pragma("unroll") for (int m_ = 0; m_ < 4; ++m_)                          \
      _Pragma("unroll") for (int n_ = 0; n_ < 4; ++n_)                        \
        acc[m_][n_] = __builtin_amdgcn_mfma_f32_16x16x32_bf16(                \
            af_[m_], BREG[s_ * 4 + n_], acc[m_][n_], 0, 0, 0);                \
  }

  // prologue
  LOADB(brA, 0);
  STAGEA(0, 0);
  __syncthreads();

  for (int kt = 0; kt < NKT; kt += 2) {
    // even phase: compute kt from buf0/brA; prefetch kt+1
    LOADB(brB, kt + 1);           // kt+1 <= 71 always
    STAGEA(1, kt + 1);
    COMPUTE(0, brA);
    __syncthreads();
    // odd phase: compute kt+1 from buf1/brB; prefetch kt+2 (clamped at end)
    const int kn = (kt + 2 < NKT) ? kt + 2 : NKT - 1;
    LOADB(brA, kn);
    STAGEA(0, kn);
    COMPUTE(1, brB);
    __syncthreads();
  }

  // epilogue: C/D col=lane&15, row=(lane>>4)*4+j
#pragma unroll
  for (int m = 0; m < 4; ++m)
#pragma unroll
    for (int n = 0; n < 4; ++n)
#pragma unroll
      for (int j = 0; j < 4; ++j)
        out[(size_t)(m0 + m * 16 + lk * 4 + j) * OUT_F + wv * 64 + n * 16 + lr] =
            acc[m][n][j];

#undef LOADB
#undef STAGEA
#undef COMPUTE
}

extern "C" void kernel_launch(void* const* d_in, const int* in_sizes, int n_in,
                              void* d_out, int out_size, void* d_ws, size_t ws_size,
                              hipStream_t stream) {
  const float* x  = (const float*)d_in[0];
  const float* bw = (const float*)d_in[1];
  const float* sw = (const float*)d_in[2];
  const float* ss = (const float*)d_in[3];
  u16* Wf = (u16*)d_ws;  // 4608*512*2B = 4.72 MB, fragment-ordered

  kan_prep<<<dim3(OUT_F * IN_F / 256), 256, 0, stream>>>(bw, sw, ss, Wf);
  kan_gemm<<<dim3(16384 / BM), 512, 0, stream>>>(x, Wf, (float*)d_out);
}

// Round 6
// 188.015 us; speedup vs baseline: 1.5070x; 1.1228x over previous
//
#include <hip/hip_runtime.h>

typedef unsigned short u16;
typedef unsigned int u32;
typedef unsigned long long u64;
typedef __attribute__((ext_vector_type(4))) float f32x4;
typedef __attribute__((ext_vector_type(8))) float f32x8;
typedef __attribute__((ext_vector_type(8))) u16 u16x8;
typedef __attribute__((ext_vector_type(8))) __bf16 bf16x8;

#define IN_F 512
#define OUT_F 512
#define BM 64
#define NKT 72      // 72 k-tiles of 64: 8 silu + 64 spline
#define NSIL 8

__device__ __forceinline__ u16 f2bf(float f) {
  u32 u = __float_as_uint(f);
  return (u16)((u + 0x7FFFu + ((u >> 16) & 1u)) >> 16);  // RNE
}
__device__ __forceinline__ float siluf(float v) { return v / (1.0f + __expf(-v)); }

// Uniform-knot cubic B-spline: 8 bf16 bases of x packed into (lo,hi) 128-bit.
__device__ __forceinline__ void spline8(float xv, u64& lo, u64& hi) {
  float u = fmaf(xv, 2.5f, 5.5f);
  float cf = floorf(u);
  float f = u - cf;
  int c = (int)cf;
  bool valid = (u >= 0.0f) && (u < 11.0f);
  c = c < 0 ? 0 : (c > 10 ? 10 : c);
  float f2 = f * f, f3 = f2 * f;
  float v1 = 1.0f - f;
  float w0 = v1 * v1 * v1 * (1.0f / 6.0f);
  float w1 = 0.5f * f3 - f2 + (2.0f / 3.0f);
  float w2 = -0.5f * f3 + 0.5f * f2 + 0.5f * f + (1.0f / 6.0f);
  float w3 = f3 * (1.0f / 6.0f);
  u64 W = (u64)f2bf(w0) | ((u64)f2bf(w1) << 16) | ((u64)f2bf(w2) << 32) |
          ((u64)f2bf(w3) << 48);
  if (!valid) W = 0;
  const int s = c * 16 - 48;
  if (s < 0)       { lo = W >> (-s); hi = 0; }
  else if (s == 0) { lo = W;         hi = 0; }
  else if (s < 64) { lo = W << s;    hi = W >> (64 - s); }
  else             { lo = 0;         hi = W << (s - 64); }
}

// Fragment-ordered weights: k-octet g (k=g*8+e), out col o:
//   u16 index = ((g>>2)*32 + (o>>4))*512 + (g&3)*128 + (o&15)*8 + e
// Thread mapping o-fast so the 16B fragment stores are 256B-contiguous per
// 16 lanes (scatter moved to the read side).
__global__ __launch_bounds__(256) void kan_prep(const float* __restrict__ bw,
                                                const float* __restrict__ sw,
                                                const float* __restrict__ ss,
                                                u16* __restrict__ Wf) {
  const int t = blockIdx.x * 256 + threadIdx.x;
  const int o = t & 511, i = t >> 9;
  const float s = ss[(size_t)o * 512 + i];
  const float* sp = sw + ((size_t)o * 512 + i) * 8;
  f32x4 s0 = *(const f32x4*)sp;
  f32x4 s1 = *(const f32x4*)(sp + 4);
  u16x8 p;
#pragma unroll
  for (int e = 0; e < 4; ++e) {
    p[e] = f2bf(s0[e] * s);
    p[4 + e] = f2bf(s1[e] * s);
  }
  const int g = 64 + i;
  *(u16x8*)&Wf[((size_t)(g >> 2) * 32 + (o >> 4)) * 512 + (g & 3) * 128 + (o & 15) * 8] = p;
  if (i < 64) {  // base-weight octets g=0..63
    const float* bp = bw + (size_t)o * 512 + i * 8;
    f32x4 b0 = *(const f32x4*)bp;
    f32x4 b1 = *(const f32x4*)(bp + 4);
    u16x8 q;
#pragma unroll
    for (int e = 0; e < 4; ++e) {
      q[e] = f2bf(b0[e]);
      q[4 + e] = f2bf(b1[e]);
    }
    *(u16x8*)&Wf[((size_t)(i >> 2) * 32 + (o >> 4)) * 512 + (i & 3) * 128 + (o & 15) * 8] = q;
  }
}

__global__ __launch_bounds__(256, 2) void kan_gemm(const float* __restrict__ x,
                                                   const u16* __restrict__ Wf,
                                                   float* __restrict__ out) {
  // A LDS, XOR layout: u16 idx = row*64 + (oct^(row&7))*8   (8KB per buffer)
  __shared__ u16 As[2][8 * 64 * 8];
  const int tid = threadIdx.x;
  const int b = blockIdx.x;
  const int nh = (b >> 2) & 1;               // XCDs 0-3 -> half 0, 4-7 -> half 1
  const int n0 = nh * 256;
  const int m0 = ((b & 3) | ((b >> 3) << 2)) * BM;

  const int lane = tid & 63;
  const int wv = tid >> 6;    // 4 waves; wave owns cols n0+wv*64 ..+63
  const int lr = lane & 15;
  const int lk = lane >> 4;

  const u16* bbase = Wf + (size_t)(nh * 16 + wv * 4) * 512 + lane * 8;

  // staging role: oct = tid&7, rows rr and rr+32
  const int oct = tid & 7;
  const int rr = tid >> 3;
  const float* xr0 = x + (size_t)(m0 + rr) * IN_F;
  const float* xr1 = xr0 + (size_t)32 * IN_F;
  const int w0off = rr * 64 + (oct ^ (rr & 7)) * 8;
  const int w1off = w0off + 32 * 64;         // (rr+32)&7 == rr&7

  const int ro0 = lr * 64 + ((lk) ^ (lr & 7)) * 8;        // s=0: oct=lk
  const int ro1 = lr * 64 + ((4 + lk) ^ (lr & 7)) * 8;    // s=1: oct=4+lk

  f32x4 acc[4][4];
  const f32x4 zero = {0.0f, 0.0f, 0.0f, 0.0f};
#pragma unroll
  for (int m = 0; m < 4; ++m)
#pragma unroll
    for (int n = 0; n < 4; ++n) acc[m][n] = zero;

  bf16x8 brA[8], brB[8];                 // [s*4+n] ping-pong B fragments
  float xvA0, xvA1, xvB0, xvB1;          // spline x prefetch (1 phase ahead)
  f32x8 xsA0, xsA1, xsB0, xsB1;          // silu x prefetch

#define LOADB(REG, KT)                                                         \
  {                                                                            \
    const u16* p_ = bbase + (size_t)(KT) * 32768;                              \
    _Pragma("unroll") for (int s_ = 0; s_ < 2; ++s_)                           \
      _Pragma("unroll") for (int n_ = 0; n_ < 4; ++n_)                         \
        REG[s_ * 4 + n_] = *(const bf16x8*)(p_ + (s_ * 32 + n_) * 512);        \
  }

#define APRE(XV0, XV1, XS0, XS1, KT)                                           \
  if ((KT) < NSIL) {                                                           \
    XS0 = *(const f32x8*)(xr0 + (KT) * 64 + oct * 8);                          \
    XS1 = *(const f32x8*)(xr1 + (KT) * 64 + oct * 8);                          \
  } else {                                                                     \
    XV0 = xr0[(KT) * 8 - 64 + oct];                                            \
    XV1 = xr1[(KT) * 8 - 64 + oct];                                            \
  }

#define AWRITE(BUF, KT, XV0, XV1, XS0, XS1)                                    \
  if ((KT) < NSIL) {                                                           \
    u16x8 p0_, p1_;                                                            \
    _Pragma("unroll") for (int e_ = 0; e_ < 8; ++e_) {                         \
      p0_[e_] = f2bf(siluf(XS0[e_]));                                          \
      p1_[e_] = f2bf(siluf(XS1[e_]));                                          \
    }                                                                          \
    *(u16x8*)&As[BUF][w0off] = p0_;                                            \
    *(u16x8*)&As[BUF][w1off] = p1_;                                            \
  } else {                                                                     \
    u64 lo_, hi_;                                                              \
    union { struct { u64 a, b; } q; u16x8 v; } uu_;                            \
    spline8(XV0, lo_, hi_);                                                    \
    uu_.q.a = lo_; uu_.q.b = hi_;                                              \
    *(u16x8*)&As[BUF][w0off] = uu_.v;                                          \
    spline8(XV1, lo_, hi_);                                                    \
    uu_.q.a = lo_; uu_.q.b = hi_;                                              \
    *(u16x8*)&As[BUF][w1off] = uu_.v;                                          \
  }

#define READAF(AF, BUF, RO)                                                    \
  _Pragma("unroll") for (int m_ = 0; m_ < 4; ++m_)                             \
    AF[m_] = *(const bf16x8*)&As[BUF][(RO) + m_ * 1024];

#define MFMAS(AF, BREG, SB)                                                    \
  __builtin_amdgcn_s_setprio(1);                                               \
  _Pragma("unroll") for (int m_ = 0; m_ < 4; ++m_)                             \
    _Pragma("unroll") for (int n_ = 0; n_ < 4; ++n_)                           \
      acc[m_][n_] = __builtin_amdgcn_mfma_f32_16x16x32_bf16(                   \
          AF[m_], BREG[(SB) + n_], acc[m_][n_], 0, 0, 0);                      \
  __builtin_amdgcn_s_setprio(0);

  // prologue: x+B+A for kt=0, then x for kt=1
  APRE(xvA0, xvA1, xsA0, xsA1, 0);
  LOADB(brA, 0);
  AWRITE(0, 0, xvA0, xvA1, xsA0, xsA1);
  APRE(xvA0, xvA1, xsA0, xsA1, 1);
  __syncthreads();

  for (int kt = 0; kt < NKT; kt += 2) {
    // ---- phase even: compute kt (buf0, brA); stage kt+1; prefetch kt+2
    {
      bf16x8 af0[4], af1[4];
      LOADB(brB, kt + 1);
      READAF(af0, 0, ro0);
      AWRITE(1, kt + 1, xvA0, xvA1, xsA0, xsA1);   // VALU overlaps ds/global latency
      if (kt + 2 < NKT) { APRE(xvB0, xvB1, xsB0, xsB1, kt + 2); }
      MFMAS(af0, brA, 0);
      READAF(af1, 0, ro1);
      MFMAS(af1, brA, 4);
    }
    __syncthreads();
    // ---- phase odd: compute kt+1 (buf1, brB); stage kt+2; prefetch kt+3
    {
      bf16x8 af0[4], af1[4];
      if (kt + 2 < NKT) { LOADB(brA, kt + 2); }
      READAF(af0, 1, ro0);
      if (kt + 2 < NKT) { AWRITE(0, kt + 2, xvB0, xvB1, xsB0, xsB1); }
      if (kt + 3 < NKT) { APRE(xvA0, xvA1, xsA0, xsA1, kt + 3); }
      MFMAS(af0, brB, 0);
      READAF(af1, 1, ro1);
      MFMAS(af1, brB, 4);
    }
    __syncthreads();
  }

  // epilogue: C/D col=lane&15, row=(lane>>4)*4+j
#pragma unroll
  for (int m = 0; m < 4; ++m)
#pragma unroll
    for (int n = 0; n < 4; ++n)
#pragma unroll
      for (int j = 0; j < 4; ++j)
        out[(size_t)(m0 + m * 16 + lk * 4 + j) * OUT_F + n0 + wv * 64 + n * 16 + lr] =
            acc[m][n][j];

#undef LOADB
#undef APRE
#undef AWRITE
#undef READAF
#undef MFMAS
}

extern "C" void kernel_launch(void* const* d_in, const int* in_sizes, int n_in,
                              void* d_out, int out_size, void* d_ws, size_t ws_size,
                              hipStream_t stream) {
  const float* x  = (const float*)d_in[0];
  const float* bw = (const float*)d_in[1];
  const float* sw = (const float*)d_in[2];
  const float* ss = (const float*)d_in[3];
  u16* Wf = (u16*)d_ws;  // 4608*512*2B = 4.72 MB, fragment-ordered

  kan_prep<<<dim3(OUT_F * IN_F / 256), 256, 0, stream>>>(bw, sw, ss, Wf);
  kan_gemm<<<dim3(512), 256, 0, stream>>>(x, Wf, (float*)d_out);
}

// Round 8
// 168.098 us; speedup vs baseline: 1.6855x; 1.1185x over previous
//
#include <hip/hip_runtime.h>

typedef unsigned char u8;
typedef unsigned short u16;
typedef unsigned int u32;
typedef unsigned long long u64;
typedef __attribute__((ext_vector_type(4))) float f32x4;
typedef __attribute__((ext_vector_type(8))) float f32x8;
typedef __attribute__((ext_vector_type(4))) u16 u16x4;
typedef __attribute__((ext_vector_type(8))) u16 u16x8;
typedef __attribute__((ext_vector_type(2))) u64 u64x2;
typedef __attribute__((ext_vector_type(8))) __bf16 bf16x8;

#define IN_F 512
#define OUT_F 512
#define BM 64
#define NSPL 64   // spline K-steps (fp8, done first)
#define NSIL 8    // silu K-steps (bf16, done second)
#define WSCALE 64.0f
#define WDESCALE 0.015625f

__device__ __forceinline__ u16 f2bf(float f) {
  u32 u = __float_as_uint(f);
  return (u16)((u + 0x7FFFu + ((u >> 16) & 1u)) >> 16);  // RNE
}
__device__ __forceinline__ float siluf(float v) { return v / (1.0f + __expf(-v)); }

// 2 floats -> 2 packed e4m3 bytes (low 16 bits of result)
__device__ __forceinline__ u32 cvtpk_fp8(float a, float b) {
  u32 d;
  asm("v_cvt_pk_fp8_f32 %0, %1, %2" : "=v"(d) : "v"(a), "v"(b));
  return d & 0xFFFFu;
}

// Uniform-knot cubic B-spline: 8 fp8 bases of x packed into a u64.
__device__ __forceinline__ u64 spl8f8(float xv) {
  float u = fmaf(xv, 2.5f, 5.5f);
  float cf = floorf(u);
  float f = u - cf;
  int c = (int)cf;
  bool valid = (u >= 0.0f) && (u < 11.0f);
  c = c < 0 ? 0 : (c > 10 ? 10 : c);
  float f2 = f * f, f3 = f2 * f, v1 = 1.0f - f;
  float w0 = v1 * v1 * v1 * (1.0f / 6.0f);
  float w1 = 0.5f * f3 - f2 + (2.0f / 3.0f);
  float w2 = -0.5f * f3 + 0.5f * f2 + 0.5f * f + (1.0f / 6.0f);
  float w3 = f3 * (1.0f / 6.0f);
  u32 lo = cvtpk_fp8(w0, w1), hi = cvtpk_fp8(w2, w3);
  u64 W = ((u64)(lo | (hi << 16))) << 24;  // w0..w3 at bytes 3..6
  int sh = (6 - c) * 8;
  u64 r = (sh >= 0) ? (W >> sh) : (W << (-sh));
  return valid ? r : 0ull;
}

// ---------------- prep: build fragment-ordered weights ----------------
// Wf8 (2MB): spline w*scaler*64 as fp8; chunk c8=(st*2+s)*32+(o>>4), 512B,
//   byte ((lk*16)+(o&15))*8+t for i=st*8+s*4+lk.
// Wf16 (512KB): base weights bf16; chunk c16=gq*32+(o>>4), 512 u16,
//   elem (g&3)*128+(o&15)*8+e for g=gq*4+(g&3), k=g*8+e.
__global__ __launch_bounds__(256) void kan_prep(const float* __restrict__ bw,
                                                const float* __restrict__ sw,
                                                const float* __restrict__ ss,
                                                u8* __restrict__ Wf8,
                                                u16* __restrict__ Wf16) {
  __shared__ u8 PL[17152];
  const int tid = threadIdx.x;
  const int b = blockIdx.x;
  if (b < 128) {
    // ---- spline region: og (16 o's) x 128 i's
    const int og = b & 31, ib = b >> 5;
    const int o_loc = tid >> 4, seg = tid & 15;
    const int orow = og * 16 + o_loc;
    const float* swp = sw + ((size_t)orow * 512 + ib * 128) * 8 + seg * 64;
    const float* ssp = ss + (size_t)orow * 512 + ib * 128;
    u8* L8 = PL;  // row stride 1048
#pragma unroll
    for (int q = 0; q < 16; ++q) {
      f32x4 v = *(const f32x4*)(swp + q * 4);
      const int el = seg * 64 + q * 4;
      float sv = ssp[el >> 3] * WSCALE;
      u32 lo = cvtpk_fp8(v[0] * sv, v[1] * sv);
      u32 hi = cvtpk_fp8(v[2] * sv, v[3] * sv);
      *(u32*)&L8[o_loc * 1048 + el] = lo | (hi << 16);
    }
    __syncthreads();
    const int s16 = tid & 31;
    const int o15a = (s16 * 2) & 15, lkv = (s16 * 2) >> 4;
#pragma unroll
    for (int cp = 0; cp < 4; ++cp) {
      const int stq_loc = cp * 8 + (tid >> 5);
      const int i_loc = stq_loc * 4 + lkv;
      u64 d0 = *(const u64*)&L8[o15a * 1048 + i_loc * 8];
      u64 d1 = *(const u64*)&L8[(o15a + 1) * 1048 + i_loc * 8];
      u64x2 dd = {d0, d1};
      *(u64x2*)&Wf8[(size_t)((ib * 32 + stq_loc) * 32 + og) * 512 + s16 * 16] = dd;
    }
  } else {
    // ---- base region: og (16 o's) x all 512 k
    const int og = b - 128;
    u16* L16 = (u16*)PL;  // row stride 536
#pragma unroll
    for (int p = 0; p < 8; ++p) {
      const int flat = tid * 4 + p * 1024;
      const int o_loc = flat >> 9, k = flat & 511;
      f32x4 v = *(const f32x4*)(bw + (size_t)(og * 16 + o_loc) * 512 + k);
      u16x4 h;
#pragma unroll
      for (int e = 0; e < 4; ++e) h[e] = f2bf(v[e]);
      *(u16x4*)&L16[o_loc * 536 + k] = h;
    }
    __syncthreads();
    const int s = tid & 63;
    const int o15 = s & 15, g3 = s >> 4;
#pragma unroll
    for (int cp = 0; cp < 4; ++cp) {
      const int gq = cp * 4 + (tid >> 6);
      u16x8 d = *(const u16x8*)&L16[o15 * 536 + (gq * 4 + g3) * 8];
      *(u16x8*)&Wf16[(size_t)(gq * 32 + og) * 512 + s * 8] = d;
    }
  }
}

// ---------------- gemm ----------------
__global__ __launch_bounds__(256, 2) void kan_gemm(const float* __restrict__ x,
                                                   const u8* __restrict__ Wf8,
                                                   const u16* __restrict__ Wf16,
                                                   float* __restrict__ out) {
  __shared__ u16 As16[2][4096];  // silu A: row*64 + (oct^(row&7))*8, u16
  __shared__ u8 As8[2][4096];    // spline A: row*64 + (oct^(row&7))*8, bytes
  const int tid = threadIdx.x;
  const int b = blockIdx.x;
  const int nh = (b >> 2) & 1;  // XCD bit -> Wf half (L2-resident)
  const int n0 = nh * 256;
  const int m0 = ((b & 3) | ((b >> 3) << 2)) * BM;

  const int lane = tid & 63;
  const int wv = tid >> 6;
  const int lr = lane & 15;
  const int lk = lane >> 4;

  const u8* b8base = Wf8 + (size_t)(nh * 16 + wv * 4) * 512 + lane * 8;
  const u16* b16base = Wf16 + (size_t)(nh * 16 + wv * 4) * 512 + lane * 8;

  const int oct = tid & 7, rr = tid >> 3;
  const float* xr0 = x + (size_t)(m0 + rr) * IN_F;
  const float* xr1 = xr0 + (size_t)32 * IN_F;
  const int woff = rr * 64 + (oct ^ (rr & 7)) * 8;           // u16 or byte units
  const int ro0 = lr * 64 + (lk ^ (lr & 7)) * 8;
  const int ro1 = lr * 64 + ((4 + lk) ^ (lr & 7)) * 8;

  f32x4 acc[4][4];
  const f32x4 zero = {0.0f, 0.0f, 0.0f, 0.0f};
#pragma unroll
  for (int m = 0; m < 4; ++m)
#pragma unroll
    for (int n = 0; n < 4; ++n) acc[m][n] = zero;

  u64 b8A[8], b8B[8];          // fp8 B frags [s*4+n]
  bf16x8 brA16[8], brB16[8];   // bf16 B frags [s*4+n]
  float xpA0, xpA1, xpB0, xpB1;
  f32x8 xsA0, xsA1, xsB0, xsB1;

#define BAR()                                              \
  {                                                        \
    asm volatile("s_waitcnt lgkmcnt(0)" ::: "memory");     \
    __builtin_amdgcn_s_barrier();                          \
  }

#define LOADB8(REG, ST)                                                        \
  {                                                                            \
    const u8* p_ = b8base + (size_t)(ST)*32768;                                \
    _Pragma("unroll") for (int s_ = 0; s_ < 2; ++s_)                           \
      _Pragma("unroll") for (int n_ = 0; n_ < 4; ++n_)                         \
        REG[s_ * 4 + n_] = *(const u64*)(p_ + s_ * 16384 + n_ * 512);          \
  }

#define LOADB16(REG, KT)                                                       \
  {                                                                            \
    const u16* p_ = b16base + (size_t)(KT)*32768;                              \
    _Pragma("unroll") for (int s_ = 0; s_ < 2; ++s_)                           \
      _Pragma("unroll") for (int n_ = 0; n_ < 4; ++n_)                         \
        REG[s_ * 4 + n_] = *(const bf16x8*)(p_ + s_ * 16384 + n_ * 512);       \
  }

#define APRE_SPL(X0, X1, ST)                                                   \
  {                                                                            \
    X0 = xr0[(ST)*8 + oct];                                                    \
    X1 = xr1[(ST)*8 + oct];                                                    \
  }

#define AWRITE_SPL(BUF, X0, X1)                                                \
  {                                                                            \
    *(u64*)&As8[BUF][woff] = spl8f8(X0);                                       \
    *(u64*)&As8[BUF][woff + 2048] = spl8f8(X1);                                \
  }

#define APRE_SIL(XS0, XS1, KT)                                                 \
  {                                                                            \
    XS0 = *(const f32x8*)(xr0 + (KT)*64 + oct * 8);                            \
    XS1 = *(const f32x8*)(xr1 + (KT)*64 + oct * 8);                            \
  }

#define AWRITE_SIL(BUF, XS0, XS1)                                              \
  {                                                                            \
    u16x8 p0_, p1_;                                                            \
    _Pragma("unroll") for (int e_ = 0; e_ < 8; ++e_) {                         \
      p0_[e_] = f2bf(siluf(XS0[e_]));                                          \
      p1_[e_] = f2bf(siluf(XS1[e_]));                                          \
    }                                                                          \
    *(u16x8*)&As16[BUF][woff] = p0_;                                           \
    *(u16x8*)&As16[BUF][woff + 2048] = p1_;                                    \
  }

#define READ8(AF, BUF, RO)                                                     \
  _Pragma("unroll") for (int m_ = 0; m_ < 4; ++m_)                             \
      AF[m_] = *(const u64*)&As8[BUF][(RO) + m_ * 1024];

#define READ16(AF, BUF, RO)                                                    \
  _Pragma("unroll") for (int m_ = 0; m_ < 4; ++m_)                             \
      AF[m_] = *(const bf16x8*)&As16[BUF][(RO) + m_ * 1024];

#define MFMA8(AF, BREG, SB)                                                    \
  __builtin_amdgcn_s_setprio(1);                                               \
  _Pragma("unroll") for (int m_ = 0; m_ < 4; ++m_)                             \
    _Pragma("unroll") for (int n_ = 0; n_ < 4; ++n_)                           \
      acc[m_][n_] = __builtin_amdgcn_mfma_f32_16x16x32_fp8_fp8(                \
          (long)AF[m_], (long)BREG[(SB) + n_], acc[m_][n_], 0, 0, 0);          \
  __builtin_amdgcn_s_setprio(0);

#define MFMA16(AF, BREG, SB)                                                   \
  __builtin_amdgcn_s_setprio(1);                                               \
  _Pragma("unroll") for (int m_ = 0; m_ < 4; ++m_)                             \
    _Pragma("unroll") for (int n_ = 0; n_ < 4; ++n_)                           \
      acc[m_][n_] = __builtin_amdgcn_mfma_f32_16x16x32_bf16(                   \
          AF[m_], BREG[(SB) + n_], acc[m_][n_], 0, 0, 0);                      \
  __builtin_amdgcn_s_setprio(0);

  // ---------- spline region prologue ----------
  APRE_SPL(xpA0, xpA1, 0);
  LOADB8(b8A, 0);
  AWRITE_SPL(0, xpA0, xpA1);
  APRE_SPL(xpB0, xpB1, 1);
  BAR();

  // ---------- spline main loop (64 fp8 K-steps) ----------
  for (int st = 0; st < NSPL; st += 2) {
    {  // even phase: compute st (buf0, b8A)
      u64 af0[4], af1[4];
      LOADB8(b8B, st + 1);
      READ8(af0, 0, ro0);
      AWRITE_SPL(1, xpB0, xpB1);                      // stages st+1
      if (st + 2 < NSPL) { APRE_SPL(xpA0, xpA1, st + 2); }
      MFMA8(af0, b8A, 0);
      READ8(af1, 0, ro1);
      MFMA8(af1, b8A, 4);
    }
    BAR();
    {  // odd phase: compute st+1 (buf1, b8B)
      u64 af0[4], af1[4];
      if (st + 2 < NSPL) { LOADB8(b8A, st + 2); }
      else { LOADB16(brA16, 0); }                     // transition: silu B
      READ8(af0, 1, ro0);
      if (st + 2 < NSPL) { AWRITE_SPL(0, xpA0, xpA1); }
      if (st + 3 < NSPL) { APRE_SPL(xpB0, xpB1, st + 3); }
      else if (st + 2 >= NSPL) { APRE_SIL(xsA0, xsA1, 0); }  // transition: silu x
      MFMA8(af0, b8B, 0);
      READ8(af1, 1, ro1);
      MFMA8(af1, b8B, 4);
    }
    BAR();
  }

  // ---------- transition: stage silu step 0, rescale acc ----------
  AWRITE_SIL(0, xsA0, xsA1);
  APRE_SIL(xsB0, xsB1, 1);
#pragma unroll
  for (int m = 0; m < 4; ++m)
#pragma unroll
    for (int n = 0; n < 4; ++n) acc[m][n] *= WDESCALE;
  BAR();

  // ---------- silu region (8 bf16 K-steps, unrolled) ----------
#define SIL_PHASE(KT, CB, CBREG, NBREG, SRC0, SRC1, TGT0, TGT1)                \
  {                                                                            \
    bf16x8 af0[4], af1[4];                                                     \
    if ((KT) < 7) { LOADB16(NBREG, (KT) + 1); }                                \
    READ16(af0, CB, ro0);                                                      \
    if ((KT) < 7) { AWRITE_SIL(((KT) + 1) & 1, SRC0, SRC1); }                  \
    if ((KT) < 6) { APRE_SIL(TGT0, TGT1, (KT) + 2); }                          \
    MFMA16(af0, CBREG, 0);                                                     \
    READ16(af1, CB, ro1);                                                      \
    MFMA16(af1, CBREG, 4);                                                     \
    if ((KT) < 7) BAR();                                                       \
  }

  SIL_PHASE(0, 0, brA16, brB16, xsB0, xsB1, xsA0, xsA1);
  SIL_PHASE(1, 1, brB16, brA16, xsA0, xsA1, xsB0, xsB1);
  SIL_PHASE(2, 0, brA16, brB16, xsB0, xsB1, xsA0, xsA1);
  SIL_PHASE(3, 1, brB16, brA16, xsA0, xsA1, xsB0, xsB1);
  SIL_PHASE(4, 0, brA16, brB16, xsB0, xsB1, xsA0, xsA1);
  SIL_PHASE(5, 1, brB16, brA16, xsA0, xsA1, xsB0, xsB1);
  SIL_PHASE(6, 0, brA16, brB16, xsB0, xsB1, xsA0, xsA1);
  SIL_PHASE(7, 1, brB16, brA16, xsA0, xsA1, xsB0, xsB1);

  // ---------- epilogue: C/D col=lane&15, row=(lane>>4)*4+j ----------
#pragma unroll
  for (int m = 0; m < 4; ++m)
#pragma unroll
    for (int n = 0; n < 4; ++n)
#pragma unroll
      for (int j = 0; j < 4; ++j)
        out[(size_t)(m0 + m * 16 + lk * 4 + j) * OUT_F + n0 + wv * 64 + n * 16 + lr] =
            acc[m][n][j];

#undef BAR
#undef LOADB8
#undef LOADB16
#undef APRE_SPL
#undef AWRITE_SPL
#undef APRE_SIL
#undef AWRITE_SIL
#undef READ8
#undef READ16
#undef MFMA8
#undef MFMA16
#undef SIL_PHASE
}

extern "C" void kernel_launch(void* const* d_in, const int* in_sizes, int n_in,
                              void* d_out, int out_size, void* d_ws, size_t ws_size,
                              hipStream_t stream) {
  const float* x  = (const float*)d_in[0];
  const float* bw = (const float*)d_in[1];
  const float* sw = (const float*)d_in[2];
  const float* ss = (const float*)d_in[3];
  u8* Wf8 = (u8*)d_ws;                          // 2 MB, fp8 spline frags
  u16* Wf16 = (u16*)((u8*)d_ws + (2u << 20));   // 512 KB, bf16 base frags

  kan_prep<<<dim3(160), 256, 0, stream>>>(bw, sw, ss, Wf8, Wf16);
  kan_gemm<<<dim3(512), 256, 0, stream>>>(x, Wf8, Wf16, (float*)d_out);
}

// Round 9
// 162.099 us; speedup vs baseline: 1.7479x; 1.0370x over previous
//
#include <hip/hip_runtime.h>

typedef unsigned char u8;
typedef unsigned short u16;
typedef unsigned int u32;
typedef unsigned long long u64;
typedef __attribute__((ext_vector_type(4))) float f32x4;
typedef __attribute__((ext_vector_type(8))) float f32x8;
typedef __attribute__((ext_vector_type(16))) float f32x16;
typedef __attribute__((ext_vector_type(8))) int i32x8;
typedef __attribute__((ext_vector_type(4))) u32 u32x4;
typedef __attribute__((ext_vector_type(8))) u16 u16x8;
typedef __attribute__((ext_vector_type(8))) __bf16 bf16x8;

#define NSPL 64    // spline K-steps of 64 (fp8 MX, first)
#define NSILST 8   // silu K-steps of 64 (bf16 32x32x16, second)
#define SCL_A 0x7F7F7F7F   // E8M0 1.0
#define SCL_B 0x79797979   // E8M0 2^-6 (descales the x64 weight pre-scale)

__device__ __forceinline__ u16 f2bf(float f) {
  u32 u = __float_as_uint(f);
  return (u16)((u + 0x7FFFu + ((u >> 16) & 1u)) >> 16);  // RNE
}
__device__ __forceinline__ float siluf(float v) { return v / (1.0f + __expf(-v)); }

__device__ __forceinline__ u32 cvtpk_fp8(float a, float b) {
  u32 d;
  asm("v_cvt_pk_fp8_f32 %0, %1, %2" : "=v"(d) : "v"(a), "v"(b));
  return d & 0xFFFFu;
}

// Uniform-knot cubic B-spline: 8 fp8 bases of x packed into a u64 (byte t = basis t).
__device__ __forceinline__ u64 spl8f8(float xv) {
  float u = fmaf(xv, 2.5f, 5.5f);
  float cf = floorf(u);
  float f = u - cf;
  int c = (int)cf;
  bool valid = (u >= 0.0f) && (u < 11.0f);
  c = c < 0 ? 0 : (c > 10 ? 10 : c);
  float f2 = f * f, f3 = f2 * f, v1 = 1.0f - f;
  float w0 = v1 * v1 * v1 * (1.0f / 6.0f);
  float w1 = 0.5f * f3 - f2 + (2.0f / 3.0f);
  float w2 = -0.5f * f3 + 0.5f * f2 + 0.5f * f + (1.0f / 6.0f);
  float w3 = f3 * (1.0f / 6.0f);
  u32 lo = cvtpk_fp8(w0, w1), hi = cvtpk_fp8(w2, w3);
  u64 W = ((u64)(lo | (hi << 16))) << 24;  // w0..w3 at bytes 3..6
  int sh = (6 - c) * 8;
  u64 r = (sh >= 0) ? (W >> sh) : (W << (-sh));
  return valid ? r : 0ull;
}

// ---------------- prep: fragment-ordered weights for 32x32 MFMA ----------------
// Wf8 (2MB): chunk (kt*16+nt) of 2KB; byte [l*32+e] = fp8(sw[o][k]*ss[o]*64),
//   o = nt*32+(l&31), k = kt*64+(l>>5)*32+e.
// Wf16b (512KB): chunk (ks*16+nt) of 1KB; u16 [l*8+e] = bf16(bw[o][ks*16+(l>>5)*8+e]).
__global__ __launch_bounds__(256) void kan_prep(const float* __restrict__ bw,
                                                const float* __restrict__ sw,
                                                const float* __restrict__ ss,
                                                u8* __restrict__ Wf8,
                                                u16* __restrict__ Wf16b) {
  const int tid = threadIdx.x, b = blockIdx.x;
  const int l = tid & 63;
  if (b < 256) {
    const int chunk = b * 4 + (tid >> 6);   // 1024 spline chunks
    const int kt = chunk >> 4, nt = chunk & 15;
    const int o = nt * 32 + (l & 31);
    const int kbase = kt * 64 + (l >> 5) * 32;
    const float* swp = sw + (size_t)o * 4096 + kbase;
    f32x4 sv4 = *(const f32x4*)(ss + (size_t)o * 512 + (kbase >> 3));
    u32 w[8];
#pragma unroll
    for (int q = 0; q < 4; ++q) {
      float s = sv4[q] * 64.0f;
      f32x8 f = *(const f32x8*)(swp + q * 8);
      w[q * 2]     = cvtpk_fp8(f[0] * s, f[1] * s) | (cvtpk_fp8(f[2] * s, f[3] * s) << 16);
      w[q * 2 + 1] = cvtpk_fp8(f[4] * s, f[5] * s) | (cvtpk_fp8(f[6] * s, f[7] * s) << 16);
    }
    u32* dst = (u32*)(Wf8 + (size_t)chunk * 2048 + l * 32);
    u32x4 d0 = {w[0], w[1], w[2], w[3]};
    u32x4 d1 = {w[4], w[5], w[6], w[7]};
    *(u32x4*)dst = d0;
    *(u32x4*)(dst + 4) = d1;
  } else {
    const int chunk = (b - 256) * 4 + (tid >> 6);  // 512 silu chunks
    const int ks = chunk >> 4, nt = chunk & 15;
    const int o = nt * 32 + (l & 31);
    const int k0 = ks * 16 + (l >> 5) * 8;
    f32x8 f = *(const f32x8*)(bw + (size_t)o * 512 + k0);
    u16x8 h;
#pragma unroll
    for (int e = 0; e < 8; ++e) h[e] = f2bf(f[e]);
    *(u16x8*)(Wf16b + (size_t)chunk * 512 + l * 8) = h;
  }
}

// ---------------- gemm ----------------
__global__ __launch_bounds__(256, 2) void kan_gemm(const float* __restrict__ x,
                                                   const u8* __restrict__ Wf8,
                                                   const u16* __restrict__ Wf16b,
                                                   float* __restrict__ out) {
  // A8: 4 chunks (mt*2+kh) x 32 rows x 40B (32B data + 8 pad) = 5120B per buffer
  __shared__ u8 As8[2][5120];
  // A16: 16 chunks (mt*8+ks*2+kh) x 32 rows x 16B = 8192B per buffer
  __shared__ u16 As16[2][4096];
  const int tid = threadIdx.x;
  const int b = blockIdx.x;
  const int nh = (b >> 2) & 1;               // XCD parity -> Wf half
  const int n0 = nh * 256;
  const int m0 = ((b & 3) | ((b >> 3) << 2)) * 64;

  const int lane = tid & 63;
  const int wv = tid >> 6;                   // 4 waves; wave tile 64x64
  const int r5 = lane & 31;
  const int kh = lane >> 5;

  const int ntbase = nh * 8 + wv * 2;
  const u8* b8base = Wf8 + (size_t)ntbase * 2048 + lane * 32;
  const u16* b16base = Wf16b + (size_t)ntbase * 512 + lane * 8;

  // staging roles
  const int sr = tid & 63;                   // row 0..63
  const int sq = tid >> 6;                   // quarter 0..3
  const float* xrow = x + (size_t)(m0 + sr) * 512;
  const int c0 = sq * 2;                     // spline cols c0, c0+1 (same chunk)
  const int w8off = ((sr >> 5) * 2 + (c0 >> 2)) * 1280 + (sr & 31) * 40 + (c0 & 3) * 8;
  const int w16off = ((sr >> 5) * 8 + sq * 2) * 256 + (sr & 31) * 8;  // kh=0; +256 for kh=1

  f32x16 acc[2][2];
  const f32x16 z16 = {0.f,0.f,0.f,0.f,0.f,0.f,0.f,0.f,0.f,0.f,0.f,0.f,0.f,0.f,0.f,0.f};
#pragma unroll
  for (int mt = 0; mt < 2; ++mt)
#pragma unroll
    for (int nt = 0; nt < 2; ++nt) acc[mt][nt] = z16;

  i32x8 b8A[2], b8B[2];        // spline B frags (nt), ping-pong
  bf16x8 brA16[8], brB16[8];   // silu B frags [ks*2+nt], ping-pong
  float xpA0, xpA1, xpB0, xpB1;
  f32x8 xsA0, xsA1, xsB0, xsB1;

#define BAR()                                            \
  {                                                      \
    asm volatile("s_waitcnt lgkmcnt(0)" ::: "memory");   \
    __builtin_amdgcn_s_barrier();                        \
  }

#define LOADB8(REG, KT)                                                        \
  {                                                                            \
    const u8* p_ = b8base + (size_t)(KT)*32768;                                \
    REG[0] = *(const i32x8*)p_;                                                \
    REG[1] = *(const i32x8*)(p_ + 2048);                                       \
  }

#define LOADB16(REG, STEP)                                                     \
  {                                                                            \
    const u16* p_ = b16base + (size_t)(STEP)*32768;                            \
    _Pragma("unroll") for (int ks_ = 0; ks_ < 4; ++ks_)                        \
      _Pragma("unroll") for (int nt_ = 0; nt_ < 2; ++nt_)                      \
        REG[ks_ * 2 + nt_] = *(const bf16x8*)(p_ + ks_ * 8192 + nt_ * 512);    \
  }

#define APRE_SPL(X0, X1, KT)                                                   \
  {                                                                            \
    X0 = xrow[(KT)*8 + c0];                                                    \
    X1 = xrow[(KT)*8 + c0 + 1];                                                \
  }

#define AWRITE_SPL(BUF, X0, X1)                                                \
  {                                                                            \
    *(u64*)&As8[BUF][w8off] = spl8f8(X0);                                      \
    *(u64*)&As8[BUF][w8off + 8] = spl8f8(X1);                                  \
  }

#define APRE_SIL(XS0, XS1, STEP)                                               \
  {                                                                            \
    XS0 = *(const f32x8*)(xrow + (STEP)*64 + sq * 16);                         \
    XS1 = *(const f32x8*)(xrow + (STEP)*64 + sq * 16 + 8);                     \
  }

#define AWRITE_SIL(BUF, XS0, XS1)                                              \
  {                                                                            \
    u16x8 p0_, p1_;                                                            \
    _Pragma("unroll") for (int e_ = 0; e_ < 8; ++e_) {                         \
      p0_[e_] = f2bf(siluf(XS0[e_]));                                          \
      p1_[e_] = f2bf(siluf(XS1[e_]));                                          \
    }                                                                          \
    *(u16x8*)&As16[BUF][w16off] = p0_;                                         \
    *(u16x8*)&As16[BUF][w16off + 256] = p1_;                                   \
  }

#define READA8(AF, BUF)                                                        \
  _Pragma("unroll") for (int mt_ = 0; mt_ < 2; ++mt_) {                        \
    const int ba_ = (mt_ * 2 + kh) * 1280 + r5 * 40;                           \
    union { u64 q[4]; i32x8 v; } uu_;                                          \
    uu_.q[0] = *(const u64*)&As8[BUF][ba_];                                    \
    uu_.q[1] = *(const u64*)&As8[BUF][ba_ + 8];                                \
    uu_.q[2] = *(const u64*)&As8[BUF][ba_ + 16];                               \
    uu_.q[3] = *(const u64*)&As8[BUF][ba_ + 24];                               \
    AF[mt_] = uu_.v;                                                           \
  }

#define MFMA_SPL(AF, BREG)                                                     \
  __builtin_amdgcn_s_setprio(1);                                               \
  _Pragma("unroll") for (int mt_ = 0; mt_ < 2; ++mt_)                          \
    _Pragma("unroll") for (int nt_ = 0; nt_ < 2; ++nt_)                        \
      acc[mt_][nt_] = __builtin_amdgcn_mfma_scale_f32_32x32x64_f8f6f4(         \
          AF[mt_], BREG[nt_], acc[mt_][nt_], 0, 0, 0, SCL_A, 0, SCL_B);        \
  __builtin_amdgcn_s_setprio(0);

#define READ16(AF, BUF, KS)                                                    \
  _Pragma("unroll") for (int mt_ = 0; mt_ < 2; ++mt_)                          \
    AF[mt_] = *(const bf16x8*)&As16[BUF][(mt_ * 8 + (KS)*2 + kh) * 256 + r5 * 8];

#define MFMA_SIL(AF, BREG, KS)                                                 \
  _Pragma("unroll") for (int mt_ = 0; mt_ < 2; ++mt_)                          \
    _Pragma("unroll") for (int nt_ = 0; nt_ < 2; ++nt_)                        \
      acc[mt_][nt_] = __builtin_amdgcn_mfma_f32_32x32x16_bf16(                 \
          AF[mt_], BREG[(KS)*2 + nt_], acc[mt_][nt_], 0, 0, 0);

  // ---------- spline prologue ----------
  APRE_SPL(xpA0, xpA1, 0);
  LOADB8(b8A, 0);
  AWRITE_SPL(0, xpA0, xpA1);
  APRE_SPL(xpB0, xpB1, 1);
  BAR();

  // ---------- spline main loop ----------
  for (int kt = 0; kt < NSPL; kt += 2) {
    {  // even: compute kt (buf0, b8A), stage kt+1
      i32x8 af[2];
      LOADB8(b8B, kt + 1);
      READA8(af, 0);
      AWRITE_SPL(1, xpB0, xpB1);
      if (kt + 2 < NSPL) { APRE_SPL(xpA0, xpA1, kt + 2); }
      MFMA_SPL(af, b8A);
    }
    BAR();
    {  // odd: compute kt+1 (buf1, b8B), stage kt+2 or transition
      i32x8 af[2];
      if (kt + 2 < NSPL) { LOADB8(b8A, kt + 2); }
      else { LOADB16(brA16, 0); }
      READA8(af, 1);
      if (kt + 2 < NSPL) { AWRITE_SPL(0, xpA0, xpA1); }
      if (kt + 3 < NSPL) { APRE_SPL(xpB0, xpB1, kt + 3); }
      else if (kt + 2 >= NSPL) { APRE_SIL(xsA0, xsA1, 0); }
      MFMA_SPL(af, b8B);
    }
    BAR();
  }

  // ---------- transition: stage silu step 0 ----------
  AWRITE_SIL(0, xsA0, xsA1);
  APRE_SIL(xsB0, xsB1, 1);
  BAR();

  // ---------- silu region (8 steps of K=64, 4 substeps each) ----------
#define SIL_PHASE(STEP, CB, CBREG, NBREG, SRC0, SRC1, TGT0, TGT1)              \
  {                                                                            \
    if ((STEP) < 7) { LOADB16(NBREG, (STEP) + 1); }                            \
    if ((STEP) < 7) { AWRITE_SIL(((STEP) + 1) & 1, SRC0, SRC1); }              \
    if ((STEP) < 6) { APRE_SIL(TGT0, TGT1, (STEP) + 2); }                      \
    __builtin_amdgcn_s_setprio(1);                                             \
    _Pragma("unroll") for (int ks_ = 0; ks_ < 4; ++ks_) {                      \
      bf16x8 af_[2];                                                           \
      READ16(af_, CB, ks_);                                                    \
      MFMA_SIL(af_, CBREG, ks_);                                               \
    }                                                                          \
    __builtin_amdgcn_s_setprio(0);                                             \
    if ((STEP) < 7) BAR();                                                     \
  }

  SIL_PHASE(0, 0, brA16, brB16, xsB0, xsB1, xsA0, xsA1);
  SIL_PHASE(1, 1, brB16, brA16, xsA0, xsA1, xsB0, xsB1);
  SIL_PHASE(2, 0, brA16, brB16, xsB0, xsB1, xsA0, xsA1);
  SIL_PHASE(3, 1, brB16, brA16, xsA0, xsA1, xsB0, xsB1);
  SIL_PHASE(4, 0, brA16, brB16, xsB0, xsB1, xsA0, xsA1);
  SIL_PHASE(5, 1, brB16, brA16, xsA0, xsA1, xsB0, xsB1);
  SIL_PHASE(6, 0, brA16, brB16, xsB0, xsB1, xsA0, xsA1);
  SIL_PHASE(7, 1, brB16, brA16, xsA0, xsA1, xsB0, xsB1);

  // ---------- epilogue: 32x32 C/D: col=lane&31, row=(reg&3)+8*(reg>>2)+4*(lane>>5) ----------
#pragma unroll
  for (int mt = 0; mt < 2; ++mt)
#pragma unroll
    for (int nt = 0; nt < 2; ++nt)
#pragma unroll
      for (int j = 0; j < 16; ++j) {
        const int row = m0 + mt * 32 + (j & 3) + ((j >> 2) << 3) + (kh << 2);
        const int col = n0 + wv * 64 + nt * 32 + r5;
        out[(size_t)row * 512 + col] = acc[mt][nt][j];
      }

#undef BAR
#undef LOADB8
#undef LOADB16
#undef APRE_SPL
#undef AWRITE_SPL
#undef APRE_SIL
#undef AWRITE_SIL
#undef READA8
#undef MFMA_SPL
#undef READ16
#undef MFMA_SIL
#undef SIL_PHASE
}

extern "C" void kernel_launch(void* const* d_in, const int* in_sizes, int n_in,
                              void* d_out, int out_size, void* d_ws, size_t ws_size,
                              hipStream_t stream) {
  const float* x  = (const float*)d_in[0];
  const float* bw = (const float*)d_in[1];
  const float* sw = (const float*)d_in[2];
  const float* ss = (const float*)d_in[3];
  u8* Wf8 = (u8*)d_ws;                          // 2 MB fp8 spline frags
  u16* Wf16b = (u16*)((u8*)d_ws + (2u << 20));  // 512 KB bf16 base frags

  kan_prep<<<dim3(384), 256, 0, stream>>>(bw, sw, ss, Wf8, Wf16b);
  kan_gemm<<<dim3(512), 256, 0, stream>>>(x, Wf8, Wf16b, (float*)d_out);
}